// Round 1
// baseline (417.569 us; speedup 1.0000x reference)
//
#include <hip/hip_runtime.h>
#include <math.h>

// Problem constants (match reference)
#define B_   16
#define C_   256
#define H_   96
#define W_   128
#define OH_  12
#define OW_  16
#define N_   192          // OH*OW
#define HID_ 128
#define Q_   4
#define PIX_ (H_*W_)      // 12288

// ---------------------------------------------------------------------------
// Kernel 1: fused avgpool(8x8) + pairwise soft-rank + soft-quantile weights
// One block per (b,c); 192 threads (one per pooled element).
// ---------------------------------------------------------------------------
__device__ __forceinline__ float block_max_192(float v, volatile float* red, int t) {
    #pragma unroll
    for (int o = 32; o; o >>= 1) v = fmaxf(v, __shfl_down(v, o, 64));
    __syncthreads();                       // protect red from previous use
    if ((t & 63) == 0) red[t >> 6] = v;
    __syncthreads();
    return fmaxf(fmaxf(red[0], red[1]), red[2]);
}

__device__ __forceinline__ float block_sum_192(float v, volatile float* red, int t) {
    #pragma unroll
    for (int o = 32; o; o >>= 1) v += __shfl_down(v, o, 64);
    __syncthreads();
    if ((t & 63) == 0) red[t >> 6] = v;
    __syncthreads();
    return red[0] + red[1] + red[2];
}

__global__ __launch_bounds__(192)
void quantile_kernel(const float* __restrict__ x, float* __restrict__ qvals) {
    const int c = blockIdx.x;
    const int b = blockIdx.y;
    const int t = threadIdx.x;

    __shared__ float fv[N_];
    __shared__ float red[3];

    const float* plane = x + (size_t)(b * C_ + c) * PIX_;

    // ---- avg pool: thread t owns bin (oh,ow) = (t/16, t%16), 8x8 window ----
    const int oh = t >> 4, ow = t & 15;
    const float* p0 = plane + oh * 8 * W_ + ow * 8;
    float s = 0.f;
    #pragma unroll
    for (int r = 0; r < 8; ++r) {
        float4 a = *reinterpret_cast<const float4*>(p0 + r * W_);
        float4 d = *reinterpret_cast<const float4*>(p0 + r * W_ + 4);
        s += a.x + a.y + a.z + a.w + d.x + d.y + d.z + d.w;
    }
    const float fi = s * (1.0f / 64.0f);
    fv[t] = fi;
    __syncthreads();

    // ---- soft rank: r_i = 1 + sum_j sigmoid((f_i - f_j)/0.1) ----
    float r_i = 1.0f;
    for (int j = 0; j < N_; ++j) {
        float d = (fi - fv[j]) * 10.0f;
        // sigmoid(d) = 1/(1+exp(-d)); rcp approx is plenty accurate here
        r_i += __builtin_amdgcn_rcpf(1.0f + __expf(-d));
    }

    // ---- soft quantile: softmax over n of -|r_n - target_q|/0.1, dot with f ----
    const float tgts[Q_] = {48.75f, 96.5f, 144.25f, 182.45f}; // 1 + q*(N-1)
    #pragma unroll
    for (int q = 0; q < Q_; ++q) {
        float lg  = -fabsf(r_i - tgts[q]) * 10.0f;
        float mx  = block_max_192(lg, red, t);
        float e   = __expf(lg - mx);
        float se  = block_sum_192(e, red, t);
        float swf = block_sum_192(e * fi, red, t);
        if (t == 0) qvals[(size_t)(b * C_ + c) * Q_ + q] = swf / se;
    }
}

// ---------------------------------------------------------------------------
// Kernel 2: tiny MLP per batch: t = relu(w1 @ qvals); t2 = <t, w2[c]>;
//           scale[b,c] = sigmoid(t2).  One block per batch, 256 threads.
// ---------------------------------------------------------------------------
__global__ __launch_bounds__(256)
void mlp_kernel(const float* __restrict__ qvals, const float* __restrict__ w1,
                const float* __restrict__ w2, float* __restrict__ scale) {
    const int b = blockIdx.x;
    const int t = threadIdx.x;

    __shared__ float ql[C_ * Q_];    // 1024
    __shared__ float tl[HID_ * Q_];  // 512

    for (int i = t; i < C_ * Q_; i += 256) ql[i] = qvals[(size_t)b * C_ * Q_ + i];
    __syncthreads();

    #pragma unroll
    for (int rep = 0; rep < 2; ++rep) {
        int idx = rep * 256 + t;          // idx = h*4 + q
        int h = idx >> 2, q = idx & 3;
        float acc = 0.f;
        for (int cc = 0; cc < C_; ++cc) acc += w1[h * C_ + cc] * ql[(cc << 2) + q];
        tl[idx] = fmaxf(acc, 0.f);
    }
    __syncthreads();

    // t2[c] = sum_{h,q} t[h,q] * w2[c,h,q]
    float acc = 0.f;
    const float* w2r = w2 + (size_t)t * (HID_ * Q_);
    for (int i = 0; i < HID_ * Q_; ++i) acc += w2r[i] * tl[i];
    scale[(size_t)b * C_ + t] = __builtin_amdgcn_rcpf(1.0f + __expf(-acc));
}

// ---------------------------------------------------------------------------
// Kernel 3: fused conv as per-batch GEMM.
//   M_b[c,k] = wf[c,k] + wf[c,C+k] * scale[b,k]   (built on the fly in LDS)
//   out[b]   = M_b @ X_b   where X_b = x[b] viewed as [C, PIX]
// fp32 tiled GEMM: 64x64 tile, BK=16, 4x4 per thread, 256 threads.
// ---------------------------------------------------------------------------
#define BM 64
#define BN 64
#define BK 16

__global__ __launch_bounds__(256)
void fuse_kernel(const float* __restrict__ x, const float* __restrict__ wf,
                 const float* __restrict__ scale, float* __restrict__ out) {
    const int pB = blockIdx.x * BN;   // pixel tile base
    const int cB = blockIdx.y * BM;   // out-channel tile base
    const int b  = blockIdx.z;
    const int t  = threadIdx.x;

    __shared__ float Ms[BM][BK + 1];
    __shared__ float Xs[BK][BN];
    __shared__ float sc[C_];

    sc[t] = scale[(size_t)b * C_ + t];   // 256 threads == C_
    __syncthreads();

    float acc[4][4] = {};
    const int tx = t & 15, ty = t >> 4;
    const size_t xbase = (size_t)b * C_ * PIX_ + pB;

    for (int kb = 0; kb < C_; kb += BK) {
        // stage M tile (64c x 16k), combining the two wf halves with scale
        #pragma unroll
        for (int i = 0; i < 4; ++i) {
            int li = t + i * 256;
            int cl = li >> 4, kl = li & 15;
            int cg = cB + cl, kg = kb + kl;
            Ms[cl][kl] = wf[(size_t)cg * 512 + kg]
                       + wf[(size_t)cg * 512 + 256 + kg] * sc[kg];
        }
        // stage X tile (16k x 64p), coalesced along p
        #pragma unroll
        for (int i = 0; i < 4; ++i) {
            int li = t + i * 256;
            int kl = li >> 6, pl = li & 63;
            Xs[kl][pl] = x[xbase + (size_t)(kb + kl) * PIX_ + pl];
        }
        __syncthreads();

        #pragma unroll
        for (int kk = 0; kk < BK; ++kk) {
            float av[4];
            #pragma unroll
            for (int j = 0; j < 4; ++j) av[j] = Ms[ty * 4 + j][kk];
            float4 bv = *reinterpret_cast<const float4*>(&Xs[kk][tx * 4]);
            float bvv[4] = {bv.x, bv.y, bv.z, bv.w};
            #pragma unroll
            for (int i = 0; i < 4; ++i)
                #pragma unroll
                for (int j = 0; j < 4; ++j)
                    acc[i][j] += av[i] * bvv[j];
        }
        __syncthreads();
    }

    #pragma unroll
    for (int i = 0; i < 4; ++i) {
        float4 v = make_float4(acc[i][0], acc[i][1], acc[i][2], acc[i][3]);
        *reinterpret_cast<float4*>(
            out + (size_t)(b * C_ + cB + ty * 4 + i) * PIX_ + pB + tx * 4) = v;
    }
}

// ---------------------------------------------------------------------------
extern "C" void kernel_launch(void* const* d_in, const int* in_sizes, int n_in,
                              void* d_out, int out_size, void* d_ws, size_t ws_size,
                              hipStream_t stream) {
    const float* x  = (const float*)d_in[0];   // [B,C,H,W]
    const float* w1 = (const float*)d_in[1];   // [HID,C]
    const float* w2 = (const float*)d_in[2];   // [C,HID,Q]
    const float* wf = (const float*)d_in[3];   // [C,2C]
    float* out = (float*)d_out;

    float* ws_qvals = (float*)d_ws;                 // B*C*Q = 16384 floats
    float* ws_scale = ws_qvals + (B_ * C_ * Q_);    // B*C   = 4096 floats

    dim3 g1(C_, B_);
    quantile_kernel<<<g1, 192, 0, stream>>>(x, ws_qvals);

    mlp_kernel<<<B_, 256, 0, stream>>>(ws_qvals, w1, w2, ws_scale);

    dim3 g3(PIX_ / BN, C_ / BM, B_);
    fuse_kernel<<<g3, 256, 0, stream>>>(x, wf, ws_scale, out);
}

// Round 2
// 188.422 us; speedup vs baseline: 2.2161x; 2.2161x over previous
//
#include <hip/hip_runtime.h>
#include <math.h>

// Problem constants (match reference)
#define B_   16
#define C_   256
#define H_   96
#define W_   128
#define OH_  12
#define OW_  16
#define N_   192          // OH*OW
#define HID_ 128
#define Q_   4
#define PIX_ (H_*W_)      // 12288

typedef __attribute__((ext_vector_type(8))) short short8;
typedef __attribute__((ext_vector_type(4))) float f32x4;

__device__ __forceinline__ ushort f2bf(float f) {
    union { float f; unsigned u; } v; v.f = f;
    unsigned r = (v.u + 0x7FFFu + ((v.u >> 16) & 1u)) >> 16;  // RNE
    return (ushort)r;
}

// ---------------------------------------------------------------------------
// Kernel 1: fused avgpool(8x8) + pairwise soft-rank + soft-quantile weights
// ---------------------------------------------------------------------------
__device__ __forceinline__ float block_max_192(float v, volatile float* red, int t) {
    #pragma unroll
    for (int o = 32; o; o >>= 1) v = fmaxf(v, __shfl_down(v, o, 64));
    __syncthreads();
    if ((t & 63) == 0) red[t >> 6] = v;
    __syncthreads();
    return fmaxf(fmaxf(red[0], red[1]), red[2]);
}

__device__ __forceinline__ float block_sum_192(float v, volatile float* red, int t) {
    #pragma unroll
    for (int o = 32; o; o >>= 1) v += __shfl_down(v, o, 64);
    __syncthreads();
    if ((t & 63) == 0) red[t >> 6] = v;
    __syncthreads();
    return red[0] + red[1] + red[2];
}

__global__ __launch_bounds__(192)
void quantile_kernel(const float* __restrict__ x, float* __restrict__ qvals) {
    const int c = blockIdx.x;
    const int b = blockIdx.y;
    const int t = threadIdx.x;

    __shared__ float fv[N_];
    __shared__ float red[3];

    const float* plane = x + (size_t)(b * C_ + c) * PIX_;

    const int oh = t >> 4, ow = t & 15;
    const float* p0 = plane + oh * 8 * W_ + ow * 8;
    float s = 0.f;
    #pragma unroll
    for (int r = 0; r < 8; ++r) {
        float4 a = *reinterpret_cast<const float4*>(p0 + r * W_);
        float4 d = *reinterpret_cast<const float4*>(p0 + r * W_ + 4);
        s += a.x + a.y + a.z + a.w + d.x + d.y + d.z + d.w;
    }
    const float fi = s * (1.0f / 64.0f);
    fv[t] = fi;
    __syncthreads();

    float r_i = 1.0f;
    for (int j = 0; j < N_; ++j) {
        float d = (fi - fv[j]) * 10.0f;
        r_i += __builtin_amdgcn_rcpf(1.0f + __expf(-d));
    }

    const float tgts[Q_] = {48.75f, 96.5f, 144.25f, 182.45f};
    #pragma unroll
    for (int q = 0; q < Q_; ++q) {
        float lg  = -fabsf(r_i - tgts[q]) * 10.0f;
        float mx  = block_max_192(lg, red, t);
        float e   = __expf(lg - mx);
        float se  = block_sum_192(e, red, t);
        float swf = block_sum_192(e * fi, red, t);
        if (t == 0) qvals[(size_t)(b * C_ + c) * Q_ + q] = swf / se;
    }
}

// ---------------------------------------------------------------------------
// Kernel 2: tiny MLP per batch -> scale[b,c]
// ---------------------------------------------------------------------------
__global__ __launch_bounds__(256)
void mlp_kernel(const float* __restrict__ qvals, const float* __restrict__ w1,
                const float* __restrict__ w2, float* __restrict__ scale) {
    const int b = blockIdx.x;
    const int t = threadIdx.x;

    __shared__ float ql[C_ * Q_];
    __shared__ float tl[HID_ * Q_];

    for (int i = t; i < C_ * Q_; i += 256) ql[i] = qvals[(size_t)b * C_ * Q_ + i];
    __syncthreads();

    #pragma unroll
    for (int rep = 0; rep < 2; ++rep) {
        int idx = rep * 256 + t;
        int h = idx >> 2, q = idx & 3;
        float acc = 0.f;
        for (int cc = 0; cc < C_; ++cc) acc += w1[h * C_ + cc] * ql[(cc << 2) + q];
        tl[idx] = fmaxf(acc, 0.f);
    }
    __syncthreads();

    float acc = 0.f;
    const float* w2r = w2 + (size_t)t * (HID_ * Q_);
    for (int i = 0; i < HID_ * Q_; ++i) acc += w2r[i] * tl[i];
    scale[(size_t)b * C_ + t] = __builtin_amdgcn_rcpf(1.0f + __expf(-acc));
}

// ---------------------------------------------------------------------------
// Kernel 2b: build M_b[c,k] = wf[c,k] + wf[c,C+k]*scale[b,k] in bf16 (to ws)
// ---------------------------------------------------------------------------
__global__ __launch_bounds__(256)
void buildM_kernel(const float* __restrict__ wf, const float* __restrict__ scale,
                   ushort* __restrict__ M) {
    const int idx = (blockIdx.x * 256 + threadIdx.x) * 8;   // into [B][C][256]
    const int b  = idx >> 16;
    const int c  = (idx >> 8) & 255;
    const int k0 = idx & 255;
    const float* w = wf + (size_t)c * (2 * C_);
    float4 a0 = *reinterpret_cast<const float4*>(w + k0);
    float4 a1 = *reinterpret_cast<const float4*>(w + k0 + 4);
    float4 g0 = *reinterpret_cast<const float4*>(w + C_ + k0);
    float4 g1 = *reinterpret_cast<const float4*>(w + C_ + k0 + 4);
    const float* sc = scale + b * C_ + k0;
    float4 s0 = *reinterpret_cast<const float4*>(sc);
    float4 s1 = *reinterpret_cast<const float4*>(sc + 4);
    short8 r;
    r[0] = (short)f2bf(a0.x + g0.x * s0.x);
    r[1] = (short)f2bf(a0.y + g0.y * s0.y);
    r[2] = (short)f2bf(a0.z + g0.z * s0.z);
    r[3] = (short)f2bf(a0.w + g0.w * s0.w);
    r[4] = (short)f2bf(a1.x + g1.x * s1.x);
    r[5] = (short)f2bf(a1.y + g1.y * s1.y);
    r[6] = (short)f2bf(a1.z + g1.z * s1.z);
    r[7] = (short)f2bf(a1.w + g1.w * s1.w);
    *reinterpret_cast<short8*>(M + idx) = r;
}

// ---------------------------------------------------------------------------
// Kernel 3 (MFMA): out[b] = M_b @ X_b in bf16/fp32-acc.
// Block: 512 threads (8 waves). Tile: 256 c (all) x 64 p, K=256 in steps of 64.
// x staged fp32->bf16 into LDS [k][p], transposed in LDS to [p][k] (XOR-swizzled)
// for ds_read_b128 B-fragments. A-fragments read directly from L2-hot M.
// ---------------------------------------------------------------------------
#define GBN 64
#define GBK 64

__global__ __launch_bounds__(512)
void mfma_fuse_kernel(const float* __restrict__ x, const ushort* __restrict__ M,
                      float* __restrict__ out) {
    const int b  = blockIdx.y;
    const int pB = blockIdx.x * GBN;
    const int t  = threadIdx.x;
    const int wave = t >> 6, lane = t & 63;
    const int lr = lane & 15, lg = lane >> 4;

    __shared__ ushort Xkp[GBK * GBN];   // [k][p]   8KB
    __shared__ ushort Bt[GBN * GBK];    // [p][k]   8KB, XOR-swizzled rows

    const int c0 = wave * 32;           // each wave owns 32 out-channels
    f32x4 acc[2][4] = {};               // [cfrag][pfrag]

    const size_t xb = (size_t)b * C_ * PIX_ + pB;
    const short* Mb = (const short*)(M + (size_t)b * C_ * C_);

    // phase-1 staging indices: thread -> (k row, 8 p's)
    const int sk = t >> 3;              // 0..63
    const int sp = (t & 7) * 8;         // 0..56
    // phase-2 transpose indices: thread -> (p column, 8 k's)
    const int tp  = t & 63;
    const int tk0 = (t >> 6) * 8;

    for (int kb = 0; kb < C_; kb += GBK) {
        // ---- phase 1: global fp32 -> bf16 LDS [k][p] (coalesced) ----
        const float* src = x + xb + (size_t)(kb + sk) * PIX_ + sp;
        float4 v0 = *reinterpret_cast<const float4*>(src);
        float4 v1 = *reinterpret_cast<const float4*>(src + 4);
        short8 pk;
        pk[0] = (short)f2bf(v0.x); pk[1] = (short)f2bf(v0.y);
        pk[2] = (short)f2bf(v0.z); pk[3] = (short)f2bf(v0.w);
        pk[4] = (short)f2bf(v1.x); pk[5] = (short)f2bf(v1.y);
        pk[6] = (short)f2bf(v1.z); pk[7] = (short)f2bf(v1.w);
        *reinterpret_cast<short8*>(&Xkp[sk * GBN + sp]) = pk;
        __syncthreads();

        // ---- phase 2: LDS transpose -> Bt[p][k] (row-sweep reads, swizzled write) ----
        short8 tv;
        #pragma unroll
        for (int j = 0; j < 8; ++j)
            tv[j] = (short)Xkp[(tk0 + j) * GBN + tp];
        *reinterpret_cast<short8*>(
            (char*)Bt + (tp * 128 + ((tk0 * 2) ^ ((tp & 7) << 4)))) = tv;
        __syncthreads();

        // ---- MFMA: 2 k-subtiles x (2 cfrag x 4 pfrag) ----
        #pragma unroll
        for (int kk = 0; kk < 2; ++kk) {
            const int ko = kb + kk * 32 + lg * 8;
            short8 a0 = *reinterpret_cast<const short8*>(Mb + (size_t)(c0 + lr) * C_ + ko);
            short8 a1 = *reinterpret_cast<const short8*>(Mb + (size_t)(c0 + 16 + lr) * C_ + ko);
            #pragma unroll
            for (int pf = 0; pf < 4; ++pf) {
                const int p = pf * 16 + lr;
                short8 bv = *reinterpret_cast<const short8*>(
                    (const char*)Bt + (p * 128 + (((kk * 32 + lg * 8) * 2) ^ ((p & 7) << 4))));
                acc[0][pf] = __builtin_amdgcn_mfma_f32_16x16x32_bf16(a0, bv, acc[0][pf], 0, 0, 0);
                acc[1][pf] = __builtin_amdgcn_mfma_f32_16x16x32_bf16(a1, bv, acc[1][pf], 0, 0, 0);
            }
        }
        __syncthreads();   // before next iter overwrites Xkp/Bt
    }

    // ---- epilogue: C/D layout col=lane&15, row=(lane>>4)*4+reg ----
    #pragma unroll
    for (int cf = 0; cf < 2; ++cf) {
        #pragma unroll
        for (int pf = 0; pf < 4; ++pf) {
            #pragma unroll
            for (int r = 0; r < 4; ++r) {
                const int c = c0 + cf * 16 + lg * 4 + r;
                out[(size_t)(b * C_ + c) * PIX_ + pB + pf * 16 + lr] = acc[cf][pf][r];
            }
        }
    }
}

// ---------------------------------------------------------------------------
// Kernel 3 fallback (fp32, round-1): used only if ws_size can't hold M.
// ---------------------------------------------------------------------------
#define BM 64
#define BN 64
#define BK 16

__global__ __launch_bounds__(256)
void fuse_kernel(const float* __restrict__ x, const float* __restrict__ wf,
                 const float* __restrict__ scale, float* __restrict__ out) {
    const int pB = blockIdx.x * BN;
    const int cB = blockIdx.y * BM;
    const int b  = blockIdx.z;
    const int t  = threadIdx.x;

    __shared__ float Ms[BM][BK + 1];
    __shared__ float Xs[BK][BN];
    __shared__ float sc[C_];

    sc[t] = scale[(size_t)b * C_ + t];
    __syncthreads();

    float acc[4][4] = {};
    const int tx = t & 15, ty = t >> 4;
    const size_t xbase = (size_t)b * C_ * PIX_ + pB;

    for (int kb = 0; kb < C_; kb += BK) {
        #pragma unroll
        for (int i = 0; i < 4; ++i) {
            int li = t + i * 256;
            int cl = li >> 4, kl = li & 15;
            int cg = cB + cl, kg = kb + kl;
            Ms[cl][kl] = wf[(size_t)cg * 512 + kg]
                       + wf[(size_t)cg * 512 + 256 + kg] * sc[kg];
        }
        #pragma unroll
        for (int i = 0; i < 4; ++i) {
            int li = t + i * 256;
            int kl = li >> 6, pl = li & 63;
            Xs[kl][pl] = x[xbase + (size_t)(kb + kl) * PIX_ + pl];
        }
        __syncthreads();

        #pragma unroll
        for (int kk = 0; kk < BK; ++kk) {
            float av[4];
            #pragma unroll
            for (int j = 0; j < 4; ++j) av[j] = Ms[ty * 4 + j][kk];
            float4 bv = *reinterpret_cast<const float4*>(&Xs[kk][tx * 4]);
            float bvv[4] = {bv.x, bv.y, bv.z, bv.w};
            #pragma unroll
            for (int i = 0; i < 4; ++i)
                #pragma unroll
                for (int j = 0; j < 4; ++j)
                    acc[i][j] += av[i] * bvv[j];
        }
        __syncthreads();
    }

    #pragma unroll
    for (int i = 0; i < 4; ++i) {
        float4 v = make_float4(acc[i][0], acc[i][1], acc[i][2], acc[i][3]);
        *reinterpret_cast<float4*>(
            out + (size_t)(b * C_ + cB + ty * 4 + i) * PIX_ + pB + tx * 4) = v;
    }
}

// ---------------------------------------------------------------------------
extern "C" void kernel_launch(void* const* d_in, const int* in_sizes, int n_in,
                              void* d_out, int out_size, void* d_ws, size_t ws_size,
                              hipStream_t stream) {
    const float* x  = (const float*)d_in[0];   // [B,C,H,W]
    const float* w1 = (const float*)d_in[1];   // [HID,C]
    const float* w2 = (const float*)d_in[2];   // [C,HID,Q]
    const float* wf = (const float*)d_in[3];   // [C,2C]
    float* out = (float*)d_out;

    float*  ws_qvals = (float*)d_ws;                      // 16384 f
    float*  ws_scale = ws_qvals + (B_ * C_ * Q_);         // 4096 f
    ushort* ws_M     = (ushort*)(ws_scale + B_ * C_);     // 1M bf16 = 2MB
    const size_t need = (size_t)(B_ * C_ * Q_ + B_ * C_) * 4
                      + (size_t)B_ * C_ * C_ * 2;

    dim3 g1(C_, B_);
    quantile_kernel<<<g1, 192, 0, stream>>>(x, ws_qvals);
    mlp_kernel<<<B_, 256, 0, stream>>>(ws_qvals, w1, w2, ws_scale);

    if (ws_size >= need) {
        buildM_kernel<<<(B_ * C_ * C_) / (256 * 8), 256, 0, stream>>>(wf, ws_scale, ws_M);
        dim3 g3(PIX_ / GBN, B_);
        mfma_fuse_kernel<<<g3, 512, 0, stream>>>(x, ws_M, out);
    } else {
        dim3 g3(PIX_ / BN, C_ / BM, B_);
        fuse_kernel<<<g3, 256, 0, stream>>>(x, wf, ws_scale, out);
    }
}